// Round 11
// baseline (130.570 us; speedup 1.0000x reference)
//
#include <hip/hip_runtime.h>

// GCNConv(8->64), self-loops, symmetric norm.
// out[c] = ( dis[c] * sum_e dis[r]*ew*x[r]  +  dis[c]^2 * x[c] ) @ W + b
//
// v11 = v10 with ILP in the latency-bound kernels (r10: aggfuse 53.5us @
// 14% HBM / 23% VALU = un-hidden latency; two serial chains):
//   * aggfuse reduce: 2-node interleave (independent accumulators, gathers
//     issued before shfl chains) -> dependent chain rounds 8 -> 4.
//   * aggfuse/nodestat stage: dual-stream halves -> global-load rounds 8 -> 4.
//
// Payload pack (u64): ew_bits(32) | row(24) | lcol(8). Valid for N <= 2^24.

#define NBMAX 1024          // max bins => N <= 131072 (fallback beyond)
#define PSH   7
#define BINSZ 128
#define TILE  6144          // edges per scatter tile (LDS: 48KB payload)
#define EPT   6             // TILE / 1024 threads
#define CAP   6144          // max edges per bin staged in LDS by B

static inline size_t ws_align(size_t x) { return (x + 255) & ~(size_t)255; }

// ---- init: zero bin counters + detect int64-vs-int32 edge_index ----
__global__ void init_k(const unsigned* w, unsigned* orw, unsigned* cnt, int E) {
    int t = threadIdx.x;              // 256 threads, 1 block
    for (int i = t; i < NBMAX; i += 256) cnt[i] = 0u;
    __shared__ unsigned s;
    if (t == 0) s = 0u;
    __syncthreads();
    unsigned v = 0;
    int lim = (E < 2048) ? E : 2048;  // stay inside buffer even if int32
    for (int i = t; i < lim; i += 256)
        v |= w[2 * i + 1];            // odd words == 0 iff int64 layout
    atomicOr(&s, v);
    __syncthreads();
    if (t == 0) *orw = s;             // 0 => int64
}

// ---- histogram over destination bins ----
__global__ void hist_k(const void* ei, const unsigned* orw, unsigned* cnt,
                       int E, int NB) {
    __shared__ unsigned lh[NBMAX];
    const bool is64 = (*orw == 0u);
    const int* e32 = (const int*)ei;
    const long long* e64 = (const long long*)ei;
    for (int i = threadIdx.x; i < NB; i += blockDim.x) lh[i] = 0u;
    __syncthreads();
    int t = blockIdx.x * blockDim.x + threadIdx.x;
    int st = gridDim.x * blockDim.x;
    for (int e = t; e < E; e += st) {
        int c = is64 ? (int)e64[E + e] : e32[E + e];
        atomicAdd(&lh[c >> PSH], 1u);
    }
    __syncthreads();
    for (int i = threadIdx.x; i < NB; i += blockDim.x) {
        unsigned v = lh[i];
        if (v) atomicAdd(&cnt[i], v);
    }
}

// ---- exclusive scan of cnt[NB] -> offs[NB+1], seed cursors (shfl) ----
__global__ void scan_k(const unsigned* cnt, unsigned* offs, unsigned* gcur, int NB) {
    __shared__ unsigned wsum[16];
    int t = threadIdx.x, lane = t & 63, wv = t >> 6;   // 1024 threads
    unsigned v0 = (t < NB) ? cnt[t] : 0u;
    unsigned s = v0;
    #pragma unroll
    for (int d = 1; d < 64; d <<= 1) {
        unsigned u = __shfl_up(s, d);
        if (lane >= d) s += u;
    }
    if (lane == 63) wsum[wv] = s;
    __syncthreads();
    if (t < 16) {
        unsigned w = wsum[t];
        #pragma unroll
        for (int d = 1; d < 16; d <<= 1) {
            unsigned u = __shfl_up(w, d, 16);
            if (t >= d) w += u;
        }
        wsum[t] = w;
    }
    __syncthreads();
    unsigned excl = s - v0 + (wv ? wsum[wv - 1] : 0u);
    if (t < NB) { offs[t] = excl; gcur[t] = excl; }
    if (t == NB - 1) offs[NB] = excl + v0;
}

// ---- tile-local counting sort -> coalesced payload writes (by bin) ----
__global__ __launch_bounds__(1024)
void scat_k(const void* ei, const float* ea, const unsigned* orw,
            unsigned* gcur, unsigned long long* pay, int E, int NB, int ntiles) {
    __shared__ unsigned long long lp[TILE];   // 48KB
    __shared__ unsigned short lbin[TILE];     // 12KB: bin of sorted element
    __shared__ unsigned lh[NBMAX];
    __shared__ unsigned lo[NBMAX];
    __shared__ unsigned gb[NBMAX];
    __shared__ unsigned wsum[16];
    const bool is64 = (*orw == 0u);
    const int* e32 = (const int*)ei;
    const long long* e64 = (const long long*)ei;
    const int t = threadIdx.x, lane = t & 63, wv = t >> 6;

    for (int tile = blockIdx.x; tile < ntiles; tile += gridDim.x) {
        int base = tile * TILE;
        int tc = E - base; if (tc > TILE) tc = TILE;

        for (int i = t; i < NB; i += 1024) lh[i] = 0u;
        __syncthreads();

        int bn[EPT]; unsigned rk[EPT]; unsigned long long pv[EPT];
        #pragma unroll
        for (int i = 0; i < EPT; ++i) {
            int e = base + i * 1024 + t;
            bn[i] = -1;
            if (e < base + tc) {
                int c, r;
                if (is64) { c = (int)e64[E + e]; r = (int)e64[e]; }
                else      { c = e32[E + e];      r = e32[e]; }
                float w = ea[e];
                bn[i] = c >> PSH;
                pv[i] = ((unsigned long long)__float_as_uint(w) << 32)
                        | ((unsigned)r << 8) | (unsigned)(c & (BINSZ - 1));
                rk[i] = atomicAdd(&lh[bn[i]], 1u);
            }
        }
        __syncthreads();

        // shfl-based inclusive scan of lh -> exclusive lo (2 barriers)
        unsigned v0 = (t < NB) ? lh[t] : 0u;
        unsigned s = v0;
        #pragma unroll
        for (int d = 1; d < 64; d <<= 1) {
            unsigned u = __shfl_up(s, d);
            if (lane >= d) s += u;
        }
        if (lane == 63) wsum[wv] = s;
        __syncthreads();
        if (t < 16) {
            unsigned w = wsum[t];
            #pragma unroll
            for (int d = 1; d < 16; d <<= 1) {
                unsigned u = __shfl_up(w, d, 16);
                if (t >= d) w += u;
            }
            wsum[t] = w;
        }
        __syncthreads();
        unsigned excl = s - v0 + (wv ? wsum[wv - 1] : 0u);
        if (t < NB) {
            lo[t] = excl;
            if (v0) gb[t] = atomicAdd(&gcur[t], v0);
        }
        __syncthreads();

        // place payloads into LDS sorted by bin, recording each slot's bin
        #pragma unroll
        for (int i = 0; i < EPT; ++i)
            if (bn[i] >= 0) {
                unsigned pos = lo[bn[i]] + rk[i];
                lp[pos] = pv[i];
                lbin[pos] = (unsigned short)bn[i];
            }
        __syncthreads();

        // flush: direct bin lookup, coalesced per-bin runs
        for (int q = t; q < tc; q += 1024) {
            int a = lbin[q];
            pay[(size_t)gb[a] + (unsigned)q - lo[a]] = lp[q];
        }
        __syncthreads();
    }
}

// ---- A: per-bin node stats -> noffs, dis, y = dis*x (dual-stream) ----
__global__ __launch_bounds__(1024)
void nodestat_k(const unsigned long long* pay, const unsigned* offs,
                unsigned* noffs, float* dis, const float* x, float* y,
                int N, int E) {
    __shared__ unsigned cnt[BINSZ];
    __shared__ float dw[BINSZ];
    __shared__ float sdis[BINSZ];
    __shared__ unsigned wpart[2];
    int b = blockIdx.x, t = threadIdx.x, lane = t & 63, wv = t >> 6;
    if (t < BINSZ) { cnt[t] = 0u; dw[t] = 0.f; }
    if (b == 0 && t == 0) noffs[N] = (unsigned)E;
    __syncthreads();
    unsigned base = offs[b], len = offs[b + 1] - base;
    unsigned half = len >> 1;
    for (unsigned j = t; j < half; j += 1024) {
        unsigned long long pA = pay[base + j];
        unsigned long long pB = pay[base + half + j];
        unsigned lcA = (unsigned)pA & 255u;
        unsigned lcB = (unsigned)pB & 255u;
        atomicAdd(&cnt[lcA], 1u);
        atomicAdd(&cnt[lcB], 1u);
        atomicAdd(&dw[lcA], __uint_as_float((unsigned)(pA >> 32)));
        atomicAdd(&dw[lcB], __uint_as_float((unsigned)(pB >> 32)));
    }
    for (unsigned j = 2 * half + t; j < len; j += 1024) {   // odd tail
        unsigned long long p = pay[base + j];
        unsigned lc = (unsigned)p & 255u;
        atomicAdd(&cnt[lc], 1u);
        atomicAdd(&dw[lc], __uint_as_float((unsigned)(p >> 32)));
    }
    __syncthreads();
    // scan 128 via 2 waves of shfl
    unsigned v0 = (t < BINSZ) ? cnt[t] : 0u;
    unsigned s = v0;
    #pragma unroll
    for (int d = 1; d < 64; d <<= 1) {
        unsigned u = __shfl_up(s, d);
        if (lane >= d) s += u;
    }
    if (t < BINSZ && lane == 63) wpart[wv] = s;
    __syncthreads();
    if (t < BINSZ) {
        unsigned excl = s - v0 + (wv == 1 ? wpart[0] : 0u);
        int node = b * BINSZ + t;
        float dval = 0.f;
        if (node < N) {
            noffs[node] = base + excl;
            float d = 1.0f + dw[t];
            dval = (d > 0.f) ? rsqrtf(d) : 0.f;
            dis[node] = dval;
        }
        sdis[t] = dval;
    }
    __syncthreads();
    int gi = b * (BINSZ * 8) + t;             // 1024 == BINSZ*8
    if (gi < N * 8) y[gi] = sdis[t >> 3] * x[gi];
}

// ---- B: fused per-bin node-sort (LDS) + aggregate + transform + out ----
// stage: dual-stream; reduce: 2-node interleave for MLP.
__global__ __launch_bounds__(1024)
void aggfuse_k(const unsigned long long* pay, const unsigned* offs,
               const unsigned* noffs, const float* dis, const float* y,
               const float* Wm, const float* bv, float* out, int N) {
    __shared__ unsigned long long lp[CAP];    // 48KB sorted payload
    __shared__ float spill[BINSZ][8];         // 4KB overflow accumulator
    __shared__ unsigned loc[BINSZ];
    __shared__ unsigned cur[BINSZ];
    const float4* y4 = (const float4*)y;
    int b = blockIdx.x, t = threadIdx.x, lane = t & 63, wv = t >> 6;
    unsigned base = offs[b], len = offs[b + 1] - base;
    ((float*)spill)[t] = 0.f;                 // 1024 floats exactly
    if (t < BINSZ) {
        int node = b * BINSZ + t;
        unsigned l = (node < N) ? (noffs[node] - base) : len;
        loc[t] = l; cur[t] = l;
    }
    __syncthreads();
    // stage: rank + place sorted-by-node into LDS (2 independent streams)
    unsigned half = len >> 1;
    for (unsigned j = t; j < half; j += 1024) {
        unsigned long long pA = pay[base + j];
        unsigned long long pB = pay[base + half + j];
        unsigned lcA = (unsigned)pA & 255u;
        unsigned lcB = (unsigned)pB & 255u;
        unsigned posA = atomicAdd(&cur[lcA], 1u);
        unsigned posB = atomicAdd(&cur[lcB], 1u);
        if (posA < CAP) lp[posA] = pA;
        else {
            unsigned r = ((unsigned)pA >> 8) & 0xFFFFFFu;
            float ew = __uint_as_float((unsigned)(pA >> 32));
            float4 u = y4[(size_t)r * 2], v = y4[(size_t)r * 2 + 1];
            atomicAdd(&spill[lcA][0], ew * u.x); atomicAdd(&spill[lcA][1], ew * u.y);
            atomicAdd(&spill[lcA][2], ew * u.z); atomicAdd(&spill[lcA][3], ew * u.w);
            atomicAdd(&spill[lcA][4], ew * v.x); atomicAdd(&spill[lcA][5], ew * v.y);
            atomicAdd(&spill[lcA][6], ew * v.z); atomicAdd(&spill[lcA][7], ew * v.w);
        }
        if (posB < CAP) lp[posB] = pB;
        else {
            unsigned r = ((unsigned)pB >> 8) & 0xFFFFFFu;
            float ew = __uint_as_float((unsigned)(pB >> 32));
            float4 u = y4[(size_t)r * 2], v = y4[(size_t)r * 2 + 1];
            atomicAdd(&spill[lcB][0], ew * u.x); atomicAdd(&spill[lcB][1], ew * u.y);
            atomicAdd(&spill[lcB][2], ew * u.z); atomicAdd(&spill[lcB][3], ew * u.w);
            atomicAdd(&spill[lcB][4], ew * v.x); atomicAdd(&spill[lcB][5], ew * v.y);
            atomicAdd(&spill[lcB][6], ew * v.z); atomicAdd(&spill[lcB][7], ew * v.w);
        }
    }
    for (unsigned j = 2 * half + t; j < len; j += 1024) {   // odd tail
        unsigned long long p = pay[base + j];
        unsigned lc = (unsigned)p & 255u;
        unsigned pos = atomicAdd(&cur[lc], 1u);
        if (pos < CAP) lp[pos] = p;
        else {
            unsigned r = ((unsigned)p >> 8) & 0xFFFFFFu;
            float ew = __uint_as_float((unsigned)(p >> 32));
            float4 u = y4[(size_t)r * 2], v = y4[(size_t)r * 2 + 1];
            atomicAdd(&spill[lc][0], ew * u.x); atomicAdd(&spill[lc][1], ew * u.y);
            atomicAdd(&spill[lc][2], ew * u.z); atomicAdd(&spill[lc][3], ew * u.w);
            atomicAdd(&spill[lc][4], ew * v.x); atomicAdd(&spill[lc][5], ew * v.y);
            atomicAdd(&spill[lc][6], ew * v.z); atomicAdd(&spill[lc][7], ew * v.w);
        }
    }
    __syncthreads();
    // reduce: wave wv handles local nodes wv+16i, two per iteration (ILP)
    float wr[8];
    #pragma unroll
    for (int k = 0; k < 8; ++k) wr[k] = Wm[k * 64 + lane];
    float bj = bv[lane];
    int slot = lane >> 1, h = lane & 1;
    for (int i = 0; i < 8; i += 2) {
        int lnA = wv + (i << 4);
        int lnB = lnA + 16;
        int nodeA = b * BINSZ + lnA;
        int nodeB = b * BINSZ + lnB;
        float a0 = 0.f, a1 = 0.f, a2 = 0.f, a3 = 0.f;
        float c0 = 0.f, c1 = 0.f, c2 = 0.f, c3 = 0.f;
        unsigned jA = 1, eA = 0, jB = 1, eB = 0;
        if (nodeA < N) {
            jA = loc[lnA] + slot;
            eA = (lnA < BINSZ - 1) ? loc[lnA + 1] : len;
            eA = eA < CAP ? eA : CAP;
        }
        if (nodeB < N) {
            jB = loc[lnB] + slot;
            eB = (lnB < BINSZ - 1) ? loc[lnB + 1] : len;
            eB = eB < CAP ? eB : CAP;
        }
        while (jA < eA || jB < eB) {
            if (jA < eA) {
                unsigned long long p = lp[jA];
                unsigned r = ((unsigned)p >> 8) & 0xFFFFFFu;
                float ew = __uint_as_float((unsigned)(p >> 32));
                float4 v = y4[(size_t)r * 2 + h];
                a0 += ew * v.x; a1 += ew * v.y; a2 += ew * v.z; a3 += ew * v.w;
            }
            if (jB < eB) {
                unsigned long long p = lp[jB];
                unsigned r = ((unsigned)p >> 8) & 0xFFFFFFu;
                float ew = __uint_as_float((unsigned)(p >> 32));
                float4 v = y4[(size_t)r * 2 + h];
                c0 += ew * v.x; c1 += ew * v.y; c2 += ew * v.z; c3 += ew * v.w;
            }
            jA += 32; jB += 32;
        }
        #pragma unroll
        for (int m = 2; m <= 32; m <<= 1) {
            a0 += __shfl_xor(a0, m); a1 += __shfl_xor(a1, m);
            a2 += __shfl_xor(a2, m); a3 += __shfl_xor(a3, m);
            c0 += __shfl_xor(c0, m); c1 += __shfl_xor(c1, m);
            c2 += __shfl_xor(c2, m); c3 += __shfl_xor(c3, m);
        }
        float rA0 = 0.f, rA1 = 0.f, rA2 = 0.f, rA3 = 0.f;
        float rB0 = 0.f, rB1 = 0.f, rB2 = 0.f, rB3 = 0.f;
        if (slot == 0 && nodeA < N) {
            float dc = dis[nodeA];
            float4 vy = y4[(size_t)nodeA * 2 + h];
            rA0 = dc * (a0 + spill[lnA][h * 4 + 0] + vy.x);
            rA1 = dc * (a1 + spill[lnA][h * 4 + 1] + vy.y);
            rA2 = dc * (a2 + spill[lnA][h * 4 + 2] + vy.z);
            rA3 = dc * (a3 + spill[lnA][h * 4 + 3] + vy.w);
        }
        if (slot == 0 && nodeB < N) {
            float dc = dis[nodeB];
            float4 vy = y4[(size_t)nodeB * 2 + h];
            rB0 = dc * (c0 + spill[lnB][h * 4 + 0] + vy.x);
            rB1 = dc * (c1 + spill[lnB][h * 4 + 1] + vy.y);
            rB2 = dc * (c2 + spill[lnB][h * 4 + 2] + vy.z);
            rB3 = dc * (c3 + spill[lnB][h * 4 + 3] + vy.w);
        }
        float gA0 = __shfl(rA0, 0), gA1 = __shfl(rA1, 0);
        float gA2 = __shfl(rA2, 0), gA3 = __shfl(rA3, 0);
        float gA4 = __shfl(rA0, 1), gA5 = __shfl(rA1, 1);
        float gA6 = __shfl(rA2, 1), gA7 = __shfl(rA3, 1);
        float gB0 = __shfl(rB0, 0), gB1 = __shfl(rB1, 0);
        float gB2 = __shfl(rB2, 0), gB3 = __shfl(rB3, 0);
        float gB4 = __shfl(rB0, 1), gB5 = __shfl(rB1, 1);
        float gB6 = __shfl(rB2, 1), gB7 = __shfl(rB3, 1);
        if (nodeA < N) {
            float o = bj + gA0 * wr[0] + gA1 * wr[1] + gA2 * wr[2] + gA3 * wr[3]
                         + gA4 * wr[4] + gA5 * wr[5] + gA6 * wr[6] + gA7 * wr[7];
            out[(size_t)nodeA * 64 + lane] = o;
        }
        if (nodeB < N) {
            float o = bj + gB0 * wr[0] + gB1 * wr[1] + gB2 * wr[2] + gB3 * wr[3]
                         + gB4 * wr[4] + gB5 * wr[5] + gB6 * wr[6] + gB7 * wr[7];
            out[(size_t)nodeB * 64 + lane] = o;
        }
    }
}

// ---------------- round-1 fallback (tiny ws / huge N) ----------------
__global__ void fb_init_k(float* deg, float4* agg4, int N) {
    int i = blockIdx.x * blockDim.x + threadIdx.x, st = gridDim.x * blockDim.x;
    for (; i < N; i += st) {
        deg[i] = 1.0f;
        agg4[2 * i] = make_float4(0.f, 0.f, 0.f, 0.f);
        agg4[2 * i + 1] = make_float4(0.f, 0.f, 0.f, 0.f);
    }
}
__global__ void fb_deg_k(const void* ei, const float* ea, const unsigned* orw,
                         float* deg, int E) {
    const bool is64 = (*orw == 0u);
    const int* e32 = (const int*)ei;
    const long long* e64 = (const long long*)ei;
    int e = blockIdx.x * blockDim.x + threadIdx.x, st = gridDim.x * blockDim.x;
    for (; e < E; e += st) {
        int c = is64 ? (int)e64[E + e] : e32[E + e];
        atomicAdd(&deg[c], ea[e]);
    }
}
__global__ void fb_dis_k(float* deg, int N) {
    int i = blockIdx.x * blockDim.x + threadIdx.x, st = gridDim.x * blockDim.x;
    for (; i < N; i += st) {
        float d = deg[i];
        deg[i] = (d > 0.f) ? rsqrtf(d) : 0.f;
    }
}
__global__ void fb_edge_k(const void* ei, const float* ea, const unsigned* orw,
                          const float* dis, const float* x, float* agg, int E) {
    const bool is64 = (*orw == 0u);
    const int* e32 = (const int*)ei;
    const long long* e64 = (const long long*)ei;
    int e = blockIdx.x * blockDim.x + threadIdx.x, st = gridDim.x * blockDim.x;
    for (; e < E; e += st) {
        int r, c;
        if (is64) { r = (int)e64[e]; c = (int)e64[E + e]; }
        else      { r = e32[e];      c = e32[E + e]; }
        float nrm = dis[r] * ea[e] * dis[c];
        const float4* xr = (const float4*)(x + (size_t)r * 8);
        float4 a = xr[0], bb = xr[1];
        float* ag = agg + (size_t)c * 8;
        atomicAdd(ag + 0, nrm * a.x);  atomicAdd(ag + 1, nrm * a.y);
        atomicAdd(ag + 2, nrm * a.z);  atomicAdd(ag + 3, nrm * a.w);
        atomicAdd(ag + 4, nrm * bb.x); atomicAdd(ag + 5, nrm * bb.y);
        atomicAdd(ag + 6, nrm * bb.z); atomicAdd(ag + 7, nrm * bb.w);
    }
}
__global__ void fb_out_k(const float* x, const float* Wm, const float* bv,
                         const float* dis, const float* agg, float* out, int N) {
    int lane = threadIdx.x & 63;
    int wid = blockIdx.x * (blockDim.x >> 6) + (threadIdx.x >> 6);
    int nw = gridDim.x * (blockDim.x >> 6);
    float wr[8];
    #pragma unroll
    for (int k = 0; k < 8; ++k) wr[k] = Wm[k * 64 + lane];
    float bj = bv[lane];
    for (int i = wid; i < N; i += nw) {
        float d = dis[i];
        float ink = 0.f;
        if (lane < 8) ink = agg[(size_t)i * 8 + lane] + d * d * x[(size_t)i * 8 + lane];
        float acc = bj;
        #pragma unroll
        for (int k = 0; k < 8; ++k) acc += __shfl(ink, k) * wr[k];
        out[(size_t)i * 64 + lane] = acc;
    }
}

extern "C" void kernel_launch(void* const* d_in, const int* in_sizes, int n_in,
                              void* d_out, int out_size, void* d_ws, size_t ws_size,
                              hipStream_t stream) {
    const float* x  = (const float*)d_in[0];
    const void*  ei = d_in[1];
    const float* ea = (const float*)d_in[2];
    const float* Wm = (const float*)d_in[3];
    const float* bv = (const float*)d_in[4];
    float* out = (float*)d_out;

    const int N = in_sizes[0] / 8;
    const int E = in_sizes[2];
    const int NB = (N + BINSZ - 1) / BINSZ;

    char* ws = (char*)d_ws;
    size_t o = 0;
    unsigned* orw   = (unsigned*)(ws + o); o += 256;
    unsigned* cnt   = (unsigned*)(ws + o); o += ws_align(NBMAX * 4);
    unsigned* offs  = (unsigned*)(ws + o); o += ws_align((NBMAX + 1) * 4);
    unsigned* gcur  = (unsigned*)(ws + o); o += ws_align(NBMAX * 4);
    float* dis      = (float*)(ws + o);    o += ws_align((size_t)N * 4);
    unsigned* noffs = (unsigned*)(ws + o); o += ws_align((size_t)(N + 1) * 4);
    float* y        = (float*)(ws + o);    o += ws_align((size_t)N * 8 * 4);
    unsigned long long* pay = (unsigned long long*)(ws + o);
    o += ws_align((size_t)E * 8);

    const int ntiles = (E + TILE - 1) / TILE;

    if (NB <= NBMAX && E >= 2048 && o <= ws_size) {
        init_k<<<1, 256, 0, stream>>>((const unsigned*)ei, orw, cnt, E);
        hist_k<<<256, 512, 0, stream>>>(ei, orw, cnt, E, NB);
        scan_k<<<1, 1024, 0, stream>>>(cnt, offs, gcur, NB);
        scat_k<<<ntiles, 1024, 0, stream>>>(ei, ea, orw, gcur, pay, E, NB, ntiles);
        nodestat_k<<<NB, 1024, 0, stream>>>(pay, offs, noffs, dis, x, y, N, E);
        aggfuse_k<<<NB, 1024, 0, stream>>>(pay, offs, noffs, dis, y, Wm, bv, out, N);
    } else {
        float* agg = (float*)(ws + 256 + ws_align((size_t)N * 4));
        init_k<<<1, 256, 0, stream>>>((const unsigned*)ei, orw, cnt, E);
        fb_init_k<<<(N + 255) / 256, 256, 0, stream>>>(dis, (float4*)agg, N);
        fb_deg_k<<<2048, 256, 0, stream>>>(ei, ea, orw, dis, E);
        fb_dis_k<<<(N + 255) / 256, 256, 0, stream>>>(dis, N);
        fb_edge_k<<<2048, 256, 0, stream>>>(ei, ea, orw, dis, x, agg, E);
        fb_out_k<<<2048, 256, 0, stream>>>(x, Wm, bv, dis, agg, out, N);
    }
}

// Round 12
// 114.486 us; speedup vs baseline: 1.1405x; 1.1405x over previous
//
#include <hip/hip_runtime.h>

// GCNConv(8->64), self-loops, symmetric norm.
// out[c] = ( dis[c] * sum_e dis[r]*ew*x[r]  +  dis[c]^2 * x[c] ) @ W + b
//
// v12 = v10 (r11 ILP reverted: it regressed) with aggfuse reduce restructured
// to cut cross-lane (LDS-pipe) ops, the r11-diagnosed bottleneck:
//   * 2 nodes per wave (lane halves), 16 slots each: 4-level shfl_xor tree
//     shared by 2 nodes -> 8 shfls/node (was 20).
//   * sag[128][8] LDS handoff + separate transform phase: full wave per node
//     does 8 broadcast LDS reads + 8 FMA (kills the 8 broadcast shfls).
//
// Payload pack (u64): ew_bits(32) | row(24) | lcol(8). Valid for N <= 2^24.

#define NBMAX 1024          // max bins => N <= 131072 (fallback beyond)
#define PSH   7
#define BINSZ 128
#define TILE  6144          // edges per scatter tile (LDS: 48KB payload)
#define EPT   6             // TILE / 1024 threads
#define CAP   6144          // max edges per bin staged in LDS by B

static inline size_t ws_align(size_t x) { return (x + 255) & ~(size_t)255; }

// ---- init: zero bin counters + detect int64-vs-int32 edge_index ----
__global__ void init_k(const unsigned* w, unsigned* orw, unsigned* cnt, int E) {
    int t = threadIdx.x;              // 256 threads, 1 block
    for (int i = t; i < NBMAX; i += 256) cnt[i] = 0u;
    __shared__ unsigned s;
    if (t == 0) s = 0u;
    __syncthreads();
    unsigned v = 0;
    int lim = (E < 2048) ? E : 2048;  // stay inside buffer even if int32
    for (int i = t; i < lim; i += 256)
        v |= w[2 * i + 1];            // odd words == 0 iff int64 layout
    atomicOr(&s, v);
    __syncthreads();
    if (t == 0) *orw = s;             // 0 => int64
}

// ---- histogram over destination bins ----
__global__ void hist_k(const void* ei, const unsigned* orw, unsigned* cnt,
                       int E, int NB) {
    __shared__ unsigned lh[NBMAX];
    const bool is64 = (*orw == 0u);
    const int* e32 = (const int*)ei;
    const long long* e64 = (const long long*)ei;
    for (int i = threadIdx.x; i < NB; i += blockDim.x) lh[i] = 0u;
    __syncthreads();
    int t = blockIdx.x * blockDim.x + threadIdx.x;
    int st = gridDim.x * blockDim.x;
    for (int e = t; e < E; e += st) {
        int c = is64 ? (int)e64[E + e] : e32[E + e];
        atomicAdd(&lh[c >> PSH], 1u);
    }
    __syncthreads();
    for (int i = threadIdx.x; i < NB; i += blockDim.x) {
        unsigned v = lh[i];
        if (v) atomicAdd(&cnt[i], v);
    }
}

// ---- exclusive scan of cnt[NB] -> offs[NB+1], seed cursors (shfl) ----
__global__ void scan_k(const unsigned* cnt, unsigned* offs, unsigned* gcur, int NB) {
    __shared__ unsigned wsum[16];
    int t = threadIdx.x, lane = t & 63, wv = t >> 6;   // 1024 threads
    unsigned v0 = (t < NB) ? cnt[t] : 0u;
    unsigned s = v0;
    #pragma unroll
    for (int d = 1; d < 64; d <<= 1) {
        unsigned u = __shfl_up(s, d);
        if (lane >= d) s += u;
    }
    if (lane == 63) wsum[wv] = s;
    __syncthreads();
    if (t < 16) {
        unsigned w = wsum[t];
        #pragma unroll
        for (int d = 1; d < 16; d <<= 1) {
            unsigned u = __shfl_up(w, d, 16);
            if (t >= d) w += u;
        }
        wsum[t] = w;
    }
    __syncthreads();
    unsigned excl = s - v0 + (wv ? wsum[wv - 1] : 0u);
    if (t < NB) { offs[t] = excl; gcur[t] = excl; }
    if (t == NB - 1) offs[NB] = excl + v0;
}

// ---- tile-local counting sort -> coalesced payload writes (by bin) ----
__global__ __launch_bounds__(1024)
void scat_k(const void* ei, const float* ea, const unsigned* orw,
            unsigned* gcur, unsigned long long* pay, int E, int NB, int ntiles) {
    __shared__ unsigned long long lp[TILE];   // 48KB
    __shared__ unsigned short lbin[TILE];     // 12KB: bin of sorted element
    __shared__ unsigned lh[NBMAX];
    __shared__ unsigned lo[NBMAX];
    __shared__ unsigned gb[NBMAX];
    __shared__ unsigned wsum[16];
    const bool is64 = (*orw == 0u);
    const int* e32 = (const int*)ei;
    const long long* e64 = (const long long*)ei;
    const int t = threadIdx.x, lane = t & 63, wv = t >> 6;

    for (int tile = blockIdx.x; tile < ntiles; tile += gridDim.x) {
        int base = tile * TILE;
        int tc = E - base; if (tc > TILE) tc = TILE;

        for (int i = t; i < NB; i += 1024) lh[i] = 0u;
        __syncthreads();

        int bn[EPT]; unsigned rk[EPT]; unsigned long long pv[EPT];
        #pragma unroll
        for (int i = 0; i < EPT; ++i) {
            int e = base + i * 1024 + t;
            bn[i] = -1;
            if (e < base + tc) {
                int c, r;
                if (is64) { c = (int)e64[E + e]; r = (int)e64[e]; }
                else      { c = e32[E + e];      r = e32[e]; }
                float w = ea[e];
                bn[i] = c >> PSH;
                pv[i] = ((unsigned long long)__float_as_uint(w) << 32)
                        | ((unsigned)r << 8) | (unsigned)(c & (BINSZ - 1));
                rk[i] = atomicAdd(&lh[bn[i]], 1u);
            }
        }
        __syncthreads();

        // shfl-based inclusive scan of lh -> exclusive lo (2 barriers)
        unsigned v0 = (t < NB) ? lh[t] : 0u;
        unsigned s = v0;
        #pragma unroll
        for (int d = 1; d < 64; d <<= 1) {
            unsigned u = __shfl_up(s, d);
            if (lane >= d) s += u;
        }
        if (lane == 63) wsum[wv] = s;
        __syncthreads();
        if (t < 16) {
            unsigned w = wsum[t];
            #pragma unroll
            for (int d = 1; d < 16; d <<= 1) {
                unsigned u = __shfl_up(w, d, 16);
                if (t >= d) w += u;
            }
            wsum[t] = w;
        }
        __syncthreads();
        unsigned excl = s - v0 + (wv ? wsum[wv - 1] : 0u);
        if (t < NB) {
            lo[t] = excl;
            if (v0) gb[t] = atomicAdd(&gcur[t], v0);
        }
        __syncthreads();

        // place payloads into LDS sorted by bin, recording each slot's bin
        #pragma unroll
        for (int i = 0; i < EPT; ++i)
            if (bn[i] >= 0) {
                unsigned pos = lo[bn[i]] + rk[i];
                lp[pos] = pv[i];
                lbin[pos] = (unsigned short)bn[i];
            }
        __syncthreads();

        // flush: direct bin lookup, coalesced per-bin runs
        for (int q = t; q < tc; q += 1024) {
            int a = lbin[q];
            pay[(size_t)gb[a] + (unsigned)q - lo[a]] = lp[q];
        }
        __syncthreads();
    }
}

// ---- A: per-bin node stats -> noffs, dis, y = dis*x ----
__global__ __launch_bounds__(1024)
void nodestat_k(const unsigned long long* pay, const unsigned* offs,
                unsigned* noffs, float* dis, const float* x, float* y,
                int N, int E) {
    __shared__ unsigned cnt[BINSZ];
    __shared__ float dw[BINSZ];
    __shared__ float sdis[BINSZ];
    __shared__ unsigned wpart[2];
    int b = blockIdx.x, t = threadIdx.x, lane = t & 63, wv = t >> 6;
    if (t < BINSZ) { cnt[t] = 0u; dw[t] = 0.f; }
    if (b == 0 && t == 0) noffs[N] = (unsigned)E;
    __syncthreads();
    unsigned base = offs[b], len = offs[b + 1] - base;
    for (unsigned j = t; j < len; j += 1024) {
        unsigned long long p = pay[base + j];
        unsigned lc = (unsigned)p & 255u;
        atomicAdd(&cnt[lc], 1u);
        atomicAdd(&dw[lc], __uint_as_float((unsigned)(p >> 32)));
    }
    __syncthreads();
    // scan 128 via 2 waves of shfl
    unsigned v0 = (t < BINSZ) ? cnt[t] : 0u;
    unsigned s = v0;
    #pragma unroll
    for (int d = 1; d < 64; d <<= 1) {
        unsigned u = __shfl_up(s, d);
        if (lane >= d) s += u;
    }
    if (t < BINSZ && lane == 63) wpart[wv] = s;
    __syncthreads();
    if (t < BINSZ) {
        unsigned excl = s - v0 + (wv == 1 ? wpart[0] : 0u);
        int node = b * BINSZ + t;
        float dval = 0.f;
        if (node < N) {
            noffs[node] = base + excl;
            float d = 1.0f + dw[t];
            dval = (d > 0.f) ? rsqrtf(d) : 0.f;
            dis[node] = dval;
        }
        sdis[t] = dval;
    }
    __syncthreads();
    int gi = b * (BINSZ * 8) + t;             // 1024 == BINSZ*8
    if (gi < N * 8) y[gi] = sdis[t >> 3] * x[gi];
}

// ---- B: fused per-bin node-sort (LDS) + aggregate + transform + out ----
// reduce: 2 nodes per wave (lane halves), 16 slots; sag handoff; transform
// phase with broadcast LDS reads (no epilogue shfls).
__global__ __launch_bounds__(1024)
void aggfuse_k(const unsigned long long* pay, const unsigned* offs,
               const unsigned* noffs, const float* dis, const float* y,
               const float* Wm, const float* bv, float* out, int N) {
    __shared__ unsigned long long lp[CAP];    // 48KB sorted payload
    __shared__ float spill[BINSZ][8];         // 4KB overflow accumulator
    __shared__ float sag[BINSZ][8];           // 4KB per-node result vector
    __shared__ unsigned loc[BINSZ];
    __shared__ unsigned cur[BINSZ];
    const float4* y4 = (const float4*)y;
    int b = blockIdx.x, t = threadIdx.x, lane = t & 63, wv = t >> 6;
    unsigned base = offs[b], len = offs[b + 1] - base;
    ((float*)spill)[t] = 0.f;                 // 1024 floats exactly
    if (t < BINSZ) {
        int node = b * BINSZ + t;
        unsigned l = (node < N) ? (noffs[node] - base) : len;
        loc[t] = l; cur[t] = l;
    }
    __syncthreads();
    // stage: rank + place sorted-by-node into LDS
    for (unsigned j = t; j < len; j += 1024) {
        unsigned long long p = pay[base + j];
        unsigned lc = (unsigned)p & 255u;
        unsigned pos = atomicAdd(&cur[lc], 1u);
        if (pos < CAP) lp[pos] = p;
        else {                                 // pathological overflow (corr.)
            unsigned r = ((unsigned)p >> 8) & 0xFFFFFFu;
            float ew = __uint_as_float((unsigned)(p >> 32));
            float4 u = y4[(size_t)r * 2], v = y4[(size_t)r * 2 + 1];
            atomicAdd(&spill[lc][0], ew * u.x); atomicAdd(&spill[lc][1], ew * u.y);
            atomicAdd(&spill[lc][2], ew * u.z); atomicAdd(&spill[lc][3], ew * u.w);
            atomicAdd(&spill[lc][4], ew * v.x); atomicAdd(&spill[lc][5], ew * v.y);
            atomicAdd(&spill[lc][6], ew * v.z); atomicAdd(&spill[lc][7], ew * v.w);
        }
    }
    __syncthreads();
    // accumulate: 2 nodes per wave, 16 slots x 2 float4-halves per node
    int half = lane >> 5;                     // 0: node A, 1: node B
    int l5 = lane & 31;
    int slot = l5 >> 1, h = l5 & 1;
    for (int i = 0; i < 4; ++i) {
        int ln = wv + ((2 * i + half) << 4);  // A: wv+32i, B: wv+32i+16
        int node = b * BINSZ + ln;
        float a0 = 0.f, a1 = 0.f, a2 = 0.f, a3 = 0.f;
        if (node < N) {
            unsigned s = loc[ln] + slot;
            unsigned e = (ln < BINSZ - 1) ? loc[ln + 1] : len;
            e = e < CAP ? e : CAP;
            for (unsigned j = s; j < e; j += 16) {
                unsigned long long p = lp[j];
                unsigned r = ((unsigned)p >> 8) & 0xFFFFFFu;
                float ew = __uint_as_float((unsigned)(p >> 32));
                float4 v = y4[(size_t)r * 2 + h];
                a0 += ew * v.x; a1 += ew * v.y; a2 += ew * v.z; a3 += ew * v.w;
            }
        }
        #pragma unroll
        for (int m = 2; m <= 16; m <<= 1) {   // within 32-lane halves
            a0 += __shfl_xor(a0, m); a1 += __shfl_xor(a1, m);
            a2 += __shfl_xor(a2, m); a3 += __shfl_xor(a3, m);
        }
        if (slot == 0 && node < N) {          // lanes 0,1 (A) and 32,33 (B)
            float dc = dis[node];
            float4 vy = y4[(size_t)node * 2 + h];
            sag[ln][h * 4 + 0] = dc * (a0 + spill[ln][h * 4 + 0] + vy.x);
            sag[ln][h * 4 + 1] = dc * (a1 + spill[ln][h * 4 + 1] + vy.y);
            sag[ln][h * 4 + 2] = dc * (a2 + spill[ln][h * 4 + 2] + vy.z);
            sag[ln][h * 4 + 3] = dc * (a3 + spill[ln][h * 4 + 3] + vy.w);
        }
    }
    __syncthreads();
    // transform: full wave per node, broadcast LDS reads, coalesced store
    float wr[8];
    #pragma unroll
    for (int k = 0; k < 8; ++k) wr[k] = Wm[k * 64 + lane];
    float bj = bv[lane];
    for (int i = 0; i < 8; ++i) {
        int ln = wv + (i << 4);
        int node = b * BINSZ + ln;
        if (node < N) {
            float o = bj;
            #pragma unroll
            for (int k = 0; k < 8; ++k) o += sag[ln][k] * wr[k];
            out[(size_t)node * 64 + lane] = o;
        }
    }
}

// ---------------- round-1 fallback (tiny ws / huge N) ----------------
__global__ void fb_init_k(float* deg, float4* agg4, int N) {
    int i = blockIdx.x * blockDim.x + threadIdx.x, st = gridDim.x * blockDim.x;
    for (; i < N; i += st) {
        deg[i] = 1.0f;
        agg4[2 * i] = make_float4(0.f, 0.f, 0.f, 0.f);
        agg4[2 * i + 1] = make_float4(0.f, 0.f, 0.f, 0.f);
    }
}
__global__ void fb_deg_k(const void* ei, const float* ea, const unsigned* orw,
                         float* deg, int E) {
    const bool is64 = (*orw == 0u);
    const int* e32 = (const int*)ei;
    const long long* e64 = (const long long*)ei;
    int e = blockIdx.x * blockDim.x + threadIdx.x, st = gridDim.x * blockDim.x;
    for (; e < E; e += st) {
        int c = is64 ? (int)e64[E + e] : e32[E + e];
        atomicAdd(&deg[c], ea[e]);
    }
}
__global__ void fb_dis_k(float* deg, int N) {
    int i = blockIdx.x * blockDim.x + threadIdx.x, st = gridDim.x * blockDim.x;
    for (; i < N; i += st) {
        float d = deg[i];
        deg[i] = (d > 0.f) ? rsqrtf(d) : 0.f;
    }
}
__global__ void fb_edge_k(const void* ei, const float* ea, const unsigned* orw,
                          const float* dis, const float* x, float* agg, int E) {
    const bool is64 = (*orw == 0u);
    const int* e32 = (const int*)ei;
    const long long* e64 = (const long long*)ei;
    int e = blockIdx.x * blockDim.x + threadIdx.x, st = gridDim.x * blockDim.x;
    for (; e < E; e += st) {
        int r, c;
        if (is64) { r = (int)e64[e]; c = (int)e64[E + e]; }
        else      { r = e32[e];      c = e32[E + e]; }
        float nrm = dis[r] * ea[e] * dis[c];
        const float4* xr = (const float4*)(x + (size_t)r * 8);
        float4 a = xr[0], bb = xr[1];
        float* ag = agg + (size_t)c * 8;
        atomicAdd(ag + 0, nrm * a.x);  atomicAdd(ag + 1, nrm * a.y);
        atomicAdd(ag + 2, nrm * a.z);  atomicAdd(ag + 3, nrm * a.w);
        atomicAdd(ag + 4, nrm * bb.x); atomicAdd(ag + 5, nrm * bb.y);
        atomicAdd(ag + 6, nrm * bb.z); atomicAdd(ag + 7, nrm * bb.w);
    }
}
__global__ void fb_out_k(const float* x, const float* Wm, const float* bv,
                         const float* dis, const float* agg, float* out, int N) {
    int lane = threadIdx.x & 63;
    int wid = blockIdx.x * (blockDim.x >> 6) + (threadIdx.x >> 6);
    int nw = gridDim.x * (blockDim.x >> 6);
    float wr[8];
    #pragma unroll
    for (int k = 0; k < 8; ++k) wr[k] = Wm[k * 64 + lane];
    float bj = bv[lane];
    for (int i = wid; i < N; i += nw) {
        float d = dis[i];
        float ink = 0.f;
        if (lane < 8) ink = agg[(size_t)i * 8 + lane] + d * d * x[(size_t)i * 8 + lane];
        float acc = bj;
        #pragma unroll
        for (int k = 0; k < 8; ++k) acc += __shfl(ink, k) * wr[k];
        out[(size_t)i * 64 + lane] = acc;
    }
}

extern "C" void kernel_launch(void* const* d_in, const int* in_sizes, int n_in,
                              void* d_out, int out_size, void* d_ws, size_t ws_size,
                              hipStream_t stream) {
    const float* x  = (const float*)d_in[0];
    const void*  ei = d_in[1];
    const float* ea = (const float*)d_in[2];
    const float* Wm = (const float*)d_in[3];
    const float* bv = (const float*)d_in[4];
    float* out = (float*)d_out;

    const int N = in_sizes[0] / 8;
    const int E = in_sizes[2];
    const int NB = (N + BINSZ - 1) / BINSZ;

    char* ws = (char*)d_ws;
    size_t o = 0;
    unsigned* orw   = (unsigned*)(ws + o); o += 256;
    unsigned* cnt   = (unsigned*)(ws + o); o += ws_align(NBMAX * 4);
    unsigned* offs  = (unsigned*)(ws + o); o += ws_align((NBMAX + 1) * 4);
    unsigned* gcur  = (unsigned*)(ws + o); o += ws_align(NBMAX * 4);
    float* dis      = (float*)(ws + o);    o += ws_align((size_t)N * 4);
    unsigned* noffs = (unsigned*)(ws + o); o += ws_align((size_t)(N + 1) * 4);
    float* y        = (float*)(ws + o);    o += ws_align((size_t)N * 8 * 4);
    unsigned long long* pay = (unsigned long long*)(ws + o);
    o += ws_align((size_t)E * 8);

    const int ntiles = (E + TILE - 1) / TILE;

    if (NB <= NBMAX && E >= 2048 && o <= ws_size) {
        init_k<<<1, 256, 0, stream>>>((const unsigned*)ei, orw, cnt, E);
        hist_k<<<256, 512, 0, stream>>>(ei, orw, cnt, E, NB);
        scan_k<<<1, 1024, 0, stream>>>(cnt, offs, gcur, NB);
        scat_k<<<ntiles, 1024, 0, stream>>>(ei, ea, orw, gcur, pay, E, NB, ntiles);
        nodestat_k<<<NB, 1024, 0, stream>>>(pay, offs, noffs, dis, x, y, N, E);
        aggfuse_k<<<NB, 1024, 0, stream>>>(pay, offs, noffs, dis, y, Wm, bv, out, N);
    } else {
        float* agg = (float*)(ws + 256 + ws_align((size_t)N * 4));
        init_k<<<1, 256, 0, stream>>>((const unsigned*)ei, orw, cnt, E);
        fb_init_k<<<(N + 255) / 256, 256, 0, stream>>>(dis, (float4*)agg, N);
        fb_deg_k<<<2048, 256, 0, stream>>>(ei, ea, orw, dis, E);
        fb_dis_k<<<(N + 255) / 256, 256, 0, stream>>>(dis, N);
        fb_edge_k<<<2048, 256, 0, stream>>>(ei, ea, orw, dis, x, agg, E);
        fb_out_k<<<2048, 256, 0, stream>>>(x, Wm, bv, dis, agg, out, N);
    }
}